// Round 1
// baseline (502.797 us; speedup 1.0000x reference)
//
#include <hip/hip_runtime.h>
#include <hip/hip_bf16.h>

// EMD loss: out[row] = sum_j ( cumsum_j(x - y) )^2, rows=262144, bins=256.
// Memory-bound: 512 MiB in / 1 MiB out -> ~85us floor at 6.3 TB/s.
// One wave (64 lanes) per row; lane i holds elements [4i, 4i+3] via float4
// (coalesced 16 B/lane). Local 4-elem prefix + 64-lane shfl_up scan +
// butterfly reduce. No LDS.

__global__ __launch_bounds__(256) void emd_loss_kernel(
    const float* __restrict__ x,
    const float* __restrict__ y,
    float* __restrict__ out,
    int nrows) {
  const int lane = threadIdx.x & 63;
  const int wave_in_block = threadIdx.x >> 6;
  const int waves_per_block = blockDim.x >> 6;
  const int wave0 = blockIdx.x * waves_per_block + wave_in_block;
  const int nwaves = gridDim.x * waves_per_block;

  for (int row = wave0; row < nrows; row += nwaves) {
    const size_t base = (size_t)row * 256;
    const float4 xv = reinterpret_cast<const float4*>(x + base)[lane];
    const float4 yv = reinterpret_cast<const float4*>(y + base)[lane];

    const float d0 = xv.x - yv.x;
    const float d1 = xv.y - yv.y;
    const float d2 = xv.z - yv.z;
    const float d3 = xv.w - yv.w;

    // local inclusive prefix over the 4 elements this lane owns
    const float p0 = d0;
    const float p1 = p0 + d1;
    const float p2 = p1 + d2;
    const float p3 = p2 + d3;

    // 64-lane inclusive scan of lane totals (p3)
    float t = p3;
#pragma unroll
    for (int off = 1; off < 64; off <<= 1) {
      float v = __shfl_up(t, off, 64);
      if (lane >= off) t += v;
    }
    const float excl = t - p3;  // exclusive prefix of lanes before us

    const float s0 = excl + p0;
    const float s1 = excl + p1;
    const float s2 = excl + p2;
    const float s3 = excl + p3;

    float acc = s0 * s0 + s1 * s1 + s2 * s2 + s3 * s3;

    // butterfly reduce across 64 lanes
#pragma unroll
    for (int off = 32; off > 0; off >>= 1) acc += __shfl_xor(acc, off, 64);

    if (lane == 0) out[row] = acc;
  }
}

extern "C" void kernel_launch(void* const* d_in, const int* in_sizes, int n_in,
                              void* d_out, int out_size, void* d_ws, size_t ws_size,
                              hipStream_t stream) {
  const float* x = (const float*)d_in[0];
  const float* y = (const float*)d_in[1];
  float* out = (float*)d_out;
  const int nrows = in_sizes[0] / 256;  // 262144

  const int block = 256;                 // 4 waves/block
  const int grid = 2048;                 // 8192 waves, 32 rows each (grid-stride)
  emd_loss_kernel<<<grid, block, 0, stream>>>(x, y, out, nrows);
}